// Round 9
// baseline (23624.857 us; speedup 1.0000x reference)
//
#include <hip/hip_runtime.h>
#include <hip/hip_bf16.h>

// Problem constants (B=256, T=512, H=512, IN=1, future=64)
#define TT  512
#define BB  256
#define HH  512
#define FUT 64
#define NBLK 128          // 32 unit-groups x 4 batch-groups

// Output dtype FP32 (r6/r7). Beacons: float 2^(20+code)*(1+m/128):
//  0: n_in!=22  1: in_sizes mismatch @m  2: ws too small  6: out_size wrong

struct Hdr { int dtflag; };

typedef __attribute__((ext_vector_type(8))) short short8;
typedef __attribute__((ext_vector_type(4))) float floatx4;

// ---- ws layout ----
#define OFF_CTR   4096
#define OFF_W     8192
#define WSZ       ((size_t)2048*512*2)          // 2MB bf16 matrix
#define OFF_H     (OFF_W + 6*WSZ)
#define HSZ       ((size_t)BB*HH*2)             // 256KB bf16 state
#define NEED_WS   (OFF_H + 4*HSZ)               // ~13.6MB

__device__ __forceinline__ float bf2f(short s) {
  unsigned u = ((unsigned)(unsigned short)s) << 16;
  return __builtin_bit_cast(float, u);
}
__device__ __forceinline__ short f2bf(float f) {
  unsigned u = __builtin_bit_cast(unsigned, f);
  u = u + 0x7FFFu + ((u >> 16) & 1u);
  return (short)(u >> 16);
}
__device__ __forceinline__ float ldf(const void* p, long i, int dt) {
  return dt ? ((const float*)p)[i] : bf2f(((const short*)p)[i]);
}

__global__ void beacon_kernel(float* dout, float v) {
  if (threadIdx.x == 0) dout[0] = v;
}

__global__ __launch_bounds__(256) void probe1_kernel(const void* w, Hdr* hdr) {
  const int tid = threadIdx.x;
  const short* s = (const short*)w;
  float mx = 0.f;
  #pragma unroll
  for (int i = 0; i < 16; ++i) {
    float v = fabsf(bf2f(s[tid * 16 + i]));
    if (!(v == v)) v = 1e30f;
    mx = fmaxf(mx, v);
  }
  #pragma unroll
  for (int off = 32; off > 0; off >>= 1) mx = fmaxf(mx, __shfl_down(mx, off));
  __shared__ float wmax[4];
  if ((tid & 63) == 0) wmax[tid >> 6] = mx;
  __syncthreads();
  if (tid == 0) {
    float m = fmaxf(fmaxf(wmax[0], wmax[1]), fmaxf(wmax[2], wmax[3]));
    hdr->dtflag = (m > 1000.f) ? 1 : 0;
  }
}

__global__ __launch_bounds__(256) void cvt_kernel(const void* src, short* dst,
                                                  const Hdr* hdr) {
  const int dt = hdr->dtflag;
  const long i = ((long)blockIdx.x * 256 + threadIdx.x);
  if (dt) {
    const float4 v = ((const float4*)src)[i];
    short4 o;
    o.x = f2bf(v.x); o.y = f2bf(v.y); o.z = f2bf(v.z); o.w = f2bf(v.w);
    ((short4*)dst)[i] = o;
  } else {
    ((short4*)dst)[i] = ((const short4*)src)[i];
  }
}

// Persistent 2-layer LSTM. 128 blocks = 32 ug x 4 bg; block owns
// (64 batches x 16 units) of c (registers) / h (global stripes).
// Wave w = n-tile w: 16 W-rows packed n = g*4+(u&3), units U0+w*4..+3.
// One grid barrier per warmup phase (L0(t) || L1(t-1) pipelined).
__global__ __launch_bounds__(256) void lstm_persist(
    const void* __restrict__ x,
    const void* __restrict__ w_ih0, const void* __restrict__ b_ih0,
    const void* __restrict__ b_hh0, const void* __restrict__ b_ih1,
    const void* __restrict__ b_hh1, const void* __restrict__ fc_w,
    const void* __restrict__ fc_b,  const void* __restrict__ pw_ih0,
    const void* __restrict__ pb_ih0, const void* __restrict__ pb_hh0,
    const void* __restrict__ pb_ih1, const void* __restrict__ pb_hh1,
    const void* __restrict__ pfc_w, const void* __restrict__ pfc_b,
    const short* __restrict__ Whh0, const short* __restrict__ Wih1,
    const short* __restrict__ Whh1, const short* __restrict__ pWhh0,
    const short* __restrict__ pWih1, const short* __restrict__ pWhh1,
    short* H0a, short* H0b, short* H1a, short* H1b,
    int* ctr, const Hdr* __restrict__ hdr, float* __restrict__ dout)
{
  const int dt  = hdr->dtflag;
  const int tid = threadIdx.x;
  const int ug  = blockIdx.x >> 2;     // 0..31
  const int bg  = blockIdx.x & 3;      // 0..3
  const int U0  = ug * 16;
  const int B0  = bg * 64;

  __shared__ float xch[64][16][4];     // gate exchange, 16KB
  __shared__ float fcl[512], pfcl[512];
  __shared__ float bsl0[64], bsl1[64], pbsl0[64], pbsl1[64];
  __shared__ float wil0[64], pwil0[64];
  __shared__ float obuf[64];

  // ---- one-time staging ----
  for (int i = tid; i < 512; i += 256) {
    fcl[i]  = ldf(fc_w, i, dt);
    pfcl[i] = ldf(pfc_w, i, dt);
  }
  if (tid < 64) {
    const int g = tid >> 4, u = tid & 15;
    const long j = (long)g*512 + U0 + u;
    bsl0[tid]  = ldf(b_ih0, j, dt) + ldf(b_hh0, j, dt);
    bsl1[tid]  = ldf(b_ih1, j, dt) + ldf(b_hh1, j, dt);
    pbsl0[tid] = ldf(pb_ih0, j, dt) + ldf(pb_hh0, j, dt);
    pbsl1[tid] = ldf(pb_ih1, j, dt) + ldf(pb_hh1, j, dt);
    wil0[tid]  = ldf(w_ih0, j, dt);
    pwil0[tid] = ldf(pw_ih0, j, dt);
  }
  __syncthreads();

  const int lane = tid & 63;
  const int wv   = tid >> 6;           // n-tile 0..3
  const int n    = lane & 15;
  const int q    = lane >> 4;
  const int gN   = n >> 2;             // gate of this n-col
  const int uN   = wv*4 + (n & 3);     // local unit 0..15
  const long wroff = ((long)gN*512 + U0 + uN) * 512 + q*8;
  const long abase = ((long)B0 + n) * 512 + q*8;

  float c0[4] = {0.f,0.f,0.f,0.f}, c1[4] = {0.f,0.f,0.f,0.f};
  const int eb  = tid >> 2;            // epilogue batch 0..63
  const int eu0 = (tid & 3) * 4;       // epilogue unit base

  short *h0c = H0a, *h0n = H0b, *h1c = H1a, *h1n = H1b;
  int ph = 0;

  // ---- helpers as macros (keep everything in one scope) ----
#define GATES(A1p, W1p, A2p, W2p, TWOSEG)                                   \
  {                                                                          \
    floatx4 acc[4] = {{0,0,0,0},{0,0,0,0},{0,0,0,0},{0,0,0,0}};              \
    {                                                                        \
      const short* wp = (W1p) + wroff;                                       \
      const short* ap = (A1p) + abase;                                       \
      _Pragma("unroll")                                                      \
      for (int kb = 0; kb < 16; ++kb) {                                      \
        short8 b8 = *(const short8*)(wp + kb*32);                            \
        _Pragma("unroll")                                                    \
        for (int mt = 0; mt < 4; ++mt) {                                     \
          short8 a8 = *(const short8*)(ap + (long)mt*16*512 + kb*32);        \
          acc[mt] = __builtin_amdgcn_mfma_f32_16x16x32_bf16(a8, b8, acc[mt], 0,0,0); \
        }                                                                    \
      }                                                                      \
    }                                                                        \
    if (TWOSEG) {                                                            \
      const short* wp = (W2p) + wroff;                                       \
      const short* ap = (A2p) + abase;                                       \
      _Pragma("unroll")                                                      \
      for (int kb = 0; kb < 16; ++kb) {                                      \
        short8 b8 = *(const short8*)(wp + kb*32);                            \
        _Pragma("unroll")                                                    \
        for (int mt = 0; mt < 4; ++mt) {                                     \
          short8 a8 = *(const short8*)(ap + (long)mt*16*512 + kb*32);        \
          acc[mt] = __builtin_amdgcn_mfma_f32_16x16x32_bf16(a8, b8, acc[mt], 0,0,0); \
        }                                                                    \
      }                                                                      \
    }                                                                        \
    __syncthreads();   /* WAR: previous epilogue finished reading xch */     \
    _Pragma("unroll")                                                        \
    for (int mt = 0; mt < 4; ++mt)                                           \
      _Pragma("unroll")                                                      \
      for (int r = 0; r < 4; ++r)                                            \
        xch[mt*16 + q*4 + r][uN][gN] = acc[mt][r];                           \
    __syncthreads();                                                         \
  }

#define EPI(BSL, WIL, MODE, TVAL, CREG, HOUT)                                \
  {                                                                          \
    float sv = 0.f;                                                          \
    if ((MODE) == 0)      sv = ldf(x, (long)(B0 + eb)*TT + (TVAL), dt);      \
    else if ((MODE) == 2) sv = obuf[eb];                                     \
    short4 hv;                                                               \
    _Pragma("unroll")                                                        \
    for (int j = 0; j < 4; ++j) {                                            \
      const int u = eu0 + j;                                                 \
      float gi = xch[eb][u][0] + (BSL)[u];                                   \
      float gf = xch[eb][u][1] + (BSL)[16+u];                                \
      float gg = xch[eb][u][2] + (BSL)[32+u];                                \
      float go = xch[eb][u][3] + (BSL)[48+u];                                \
      if ((MODE) != 1) {                                                     \
        gi += sv*(WIL)[u];  gf += sv*(WIL)[16+u];                            \
        gg += sv*(WIL)[32+u]; go += sv*(WIL)[48+u];                          \
      }                                                                      \
      const float I = 1.f/(1.f+expf(-gi));                                   \
      const float F = 1.f/(1.f+expf(-gf));                                   \
      const float G = tanhf(gg);                                             \
      const float O = 1.f/(1.f+expf(-go));                                   \
      const float cn = F*(CREG)[j] + I*G;                                    \
      (CREG)[j] = cn;                                                        \
      ((short*)&hv)[j] = f2bf(O * tanhf(cn));                                \
    }                                                                        \
    *(short4*)((HOUT) + (long)(B0+eb)*512 + U0 + eu0) = hv;                  \
  }

#define GBAR()                                                               \
  {                                                                          \
    __syncthreads();                                                         \
    ++ph;                                                                    \
    if (tid == 0) {                                                          \
      __threadfence();                                                       \
      __hip_atomic_fetch_add(ctr, 1, __ATOMIC_RELEASE,                       \
                             __HIP_MEMORY_SCOPE_AGENT);                      \
      while (__hip_atomic_load(ctr, __ATOMIC_ACQUIRE,                        \
                               __HIP_MEMORY_SCOPE_AGENT) < ph * NBLK)        \
        __builtin_amdgcn_s_sleep(4);                                         \
      __threadfence();                                                       \
    }                                                                        \
    __syncthreads();                                                         \
  }

#define HEAD(H1C, FW, FB, S)                                                 \
  {                                                                          \
    const int hb = tid >> 2, seg = tid & 3;                                  \
    const short* hp = (H1C) + (long)(B0+hb)*512 + seg*128;                   \
    float sum = 0.f;                                                         \
    _Pragma("unroll")                                                        \
    for (int i = 0; i < 16; ++i) {                                           \
      short8 h8 = *(const short8*)(hp + i*8);                                \
      _Pragma("unroll")                                                      \
      for (int j = 0; j < 8; ++j) sum += bf2f(h8[j]) * (FW)[seg*128+i*8+j];  \
    }                                                                        \
    sum += __shfl_xor(sum, 1);                                               \
    sum += __shfl_xor(sum, 2);                                               \
    if (seg == 0) {                                                          \
      float o = sum + ldf((FB), 0, dt);                                      \
      obuf[hb] = o;                                                          \
      if (ug == 0) dout[(long)(B0+hb)*FUT + (S)] = o;                        \
    }                                                                        \
    __syncthreads();                                                         \
  }

  // ---- warmup: phase t = L0(t) || L1(t-1), one barrier each ----
  for (int t = 0; t < TT; ++t) {
    GATES(h0c, Whh0, h0c, Whh0, 0);
    EPI(bsl0, wil0, 0, t, c0, h0n);
    if (t > 0) {
      GATES(h0c, Wih1, h1c, Whh1, 1);
      EPI(bsl1, wil0, 1, 0, c1, h1n);
      { short* tmp = h1c; h1c = h1n; h1n = tmp; }
    }
    { short* tmp = h0c; h0c = h0n; h0n = tmp; }
    GBAR();
  }
  // final L1(511)
  GATES(h0c, Wih1, h1c, Whh1, 1);
  EPI(bsl1, wil0, 1, 0, c1, h1n);
  { short* tmp = h1c; h1c = h1n; h1n = tmp; }
  GBAR();

  HEAD(h1c, fcl, fc_b, 0);

  // ---- decode: 63 steps, 2 barriers each ----
  for (int s = 1; s < FUT; ++s) {
    GATES(h0c, pWhh0, h0c, pWhh0, 0);
    EPI(pbsl0, pwil0, 2, 0, c0, h0n);
    { short* tmp = h0c; h0c = h0n; h0n = tmp; }
    GBAR();
    GATES(h0c, pWih1, h1c, pWhh1, 1);
    EPI(pbsl1, pwil0, 1, 0, c1, h1n);
    { short* tmp = h1c; h1c = h1n; h1n = tmp; }
    GBAR();
    HEAD(h1c, pfcl, pfc_b, s);
  }
#undef GATES
#undef EPI
#undef GBAR
#undef HEAD
}

extern "C" void kernel_launch(void* const* d_in, const int* in_sizes, int n_in,
                              void* d_out, int out_size, void* d_ws, size_t ws_size,
                              hipStream_t stream) {
  float* dout = (float*)d_out;

  static const int exp_sizes[22] = {
    131072, 1, 2048, 1048576, 2048, 2048, 1048576, 1048576, 2048, 2048,
    512, 1, 2048, 1048576, 2048, 2048, 1048576, 1048576, 2048, 2048, 512, 1};
  int code = -1, m = 0;
  if (n_in != 22) { code = 0; m = n_in & 127; }
  else {
    for (int i = 0; i < 22; ++i)
      if (in_sizes[i] != exp_sizes[i]) { code = 1; m = i; break; }
  }
  if (code < 0 && out_size != BB * FUT) { code = 6; m = (out_size >> 8) & 127; }
  if (code < 0 && (d_ws == nullptr || ws_size < NEED_WS)) {
    code = 2; m = (int)(ws_size >> 20); if (m > 127) m = 127;
  }
  if (code >= 0) {
    float v = ldexpf(1.f + (float)m / 128.f, 20 + code);
    beacon_kernel<<<dim3(1), dim3(64), 0, stream>>>(dout, v);
    return;
  }

  const void* x      = d_in[0];
  const void* w_ih0  = d_in[2];
  const void* w_hh0  = d_in[3];
  const void* b_ih0  = d_in[4];
  const void* b_hh0  = d_in[5];
  const void* w_ih1  = d_in[6];
  const void* w_hh1  = d_in[7];
  const void* b_ih1  = d_in[8];
  const void* b_hh1  = d_in[9];
  const void* fc_w   = d_in[10];
  const void* fc_b   = d_in[11];
  const void* pw_ih0 = d_in[12];
  const void* pw_hh0 = d_in[13];
  const void* pb_ih0 = d_in[14];
  const void* pb_hh0 = d_in[15];
  const void* pw_ih1 = d_in[16];
  const void* pw_hh1 = d_in[17];
  const void* pb_ih1 = d_in[18];
  const void* pb_hh1 = d_in[19];
  const void* pfc_w  = d_in[20];
  const void* pfc_b  = d_in[21];

  char* ws = (char*)d_ws;
  Hdr* hdr = (Hdr*)ws;
  int* ctr = (int*)(ws + OFF_CTR);
  short* Wc[6];
  for (int i = 0; i < 6; ++i) Wc[i] = (short*)(ws + OFF_W + (size_t)i*WSZ);
  short* H0a = (short*)(ws + OFF_H);
  short* H0b = (short*)(ws + OFF_H + HSZ);
  short* H1a = (short*)(ws + OFF_H + 2*HSZ);
  short* H1b = (short*)(ws + OFF_H + 3*HSZ);

  hipMemsetAsync(ws, 0, 8192, stream);          // hdr + barrier counter
  hipMemsetAsync(H0a, 0, HSZ, stream);
  hipMemsetAsync(H1a, 0, HSZ, stream);
  probe1_kernel<<<dim3(1), dim3(256), 0, stream>>>(w_hh0, hdr);

  dim3 cg(1024), cb(256);
  cvt_kernel<<<cg, cb, 0, stream>>>(w_hh0,  Wc[0], hdr);
  cvt_kernel<<<cg, cb, 0, stream>>>(w_ih1,  Wc[1], hdr);
  cvt_kernel<<<cg, cb, 0, stream>>>(w_hh1,  Wc[2], hdr);
  cvt_kernel<<<cg, cb, 0, stream>>>(pw_hh0, Wc[3], hdr);
  cvt_kernel<<<cg, cb, 0, stream>>>(pw_ih1, Wc[4], hdr);
  cvt_kernel<<<cg, cb, 0, stream>>>(pw_hh1, Wc[5], hdr);

  lstm_persist<<<dim3(NBLK), dim3(256), 0, stream>>>(
      x, w_ih0, b_ih0, b_hh0, b_ih1, b_hh1, fc_w, fc_b,
      pw_ih0, pb_ih0, pb_hh0, pb_ih1, pb_hh1, pfc_w, pfc_b,
      Wc[0], Wc[1], Wc[2], Wc[3], Wc[4], Wc[5],
      H0a, H0b, H1a, H1b, ctr, hdr, dout);
}

// Round 10
// 17682.590 us; speedup vs baseline: 1.3361x; 1.3361x over previous
//
#include <hip/hip_runtime.h>
#include <hip/hip_bf16.h>

// Problem constants (B=256, T=512, H=512, IN=1, future=64)
#define TT  512
#define BB  256
#define HH  512
#define FUT 64
#define NBLK 256           // 128 unit-groups x 2 batch-groups

// Output dtype FP32 (r6/r7 verified). Beacons: float 2^(20+code)*(1+m/128):
//  0: n_in!=22  1: in_sizes mismatch @m  2: ws too small  6: out_size wrong

struct Hdr { int dtflag; };

typedef __attribute__((ext_vector_type(8))) short short8;
typedef __attribute__((ext_vector_type(4))) float floatx4;

#define OFF_CTR   4096
#define OFF_W     8192
#define WSZ       ((size_t)2048*512*2)          // 2MB bf16 matrix
#define OFF_H     (OFF_W + 6*WSZ)
#define HSZ       ((size_t)BB*HH*2)             // 256KB bf16 state
#define NEED_WS   (OFF_H + 4*HSZ)               // ~13.6MB

__device__ __forceinline__ float bf2f(short s) {
  unsigned u = ((unsigned)(unsigned short)s) << 16;
  return __builtin_bit_cast(float, u);
}
__device__ __forceinline__ short f2bf(float f) {
  unsigned u = __builtin_bit_cast(unsigned, f);
  u = u + 0x7FFFu + ((u >> 16) & 1u);
  return (short)(u >> 16);
}
__device__ __forceinline__ float ldf(const void* p, long i, int dt) {
  return dt ? ((const float*)p)[i] : bf2f(((const short*)p)[i]);
}

__global__ void beacon_kernel(float* dout, float v) {
  if (threadIdx.x == 0) dout[0] = v;
}

__global__ __launch_bounds__(256) void probe1_kernel(const void* w, Hdr* hdr) {
  const int tid = threadIdx.x;
  const short* s = (const short*)w;
  float mx = 0.f;
  #pragma unroll
  for (int i = 0; i < 16; ++i) {
    float v = fabsf(bf2f(s[tid * 16 + i]));
    if (!(v == v)) v = 1e30f;
    mx = fmaxf(mx, v);
  }
  #pragma unroll
  for (int off = 32; off > 0; off >>= 1) mx = fmaxf(mx, __shfl_down(mx, off));
  __shared__ float wmax[4];
  if ((tid & 63) == 0) wmax[tid >> 6] = mx;
  __syncthreads();
  if (tid == 0) {
    float m = fmaxf(fmaxf(wmax[0], wmax[1]), fmaxf(wmax[2], wmax[3]));
    hdr->dtflag = (m > 1000.f) ? 1 : 0;
  }
}

__global__ __launch_bounds__(256) void cvt_kernel(const void* src, short* dst,
                                                  const Hdr* hdr) {
  const int dt = hdr->dtflag;
  const long i = ((long)blockIdx.x * 256 + threadIdx.x);
  if (dt) {
    const float4 v = ((const float4*)src)[i];
    short4 o;
    o.x = f2bf(v.x); o.y = f2bf(v.y); o.z = f2bf(v.z); o.w = f2bf(v.w);
    ((short4*)dst)[i] = o;
  } else {
    ((short4*)dst)[i] = ((const short4*)src)[i];
  }
}

// Persistent 2-layer LSTM, LDS-resident weights.
// 256 blocks = 128 ug x 2 bg. Block owns 4 units x 128 batches.
// W slice: 16 rows (4 gates x 4 units) x K=512, fragment-major in LDS.
// Barrier: two-level (8 groups x 32 + root), fence-based sync.
__global__ __launch_bounds__(256) void lstm_persist(
    const void* __restrict__ x,
    const void* __restrict__ w_ih0, const void* __restrict__ b_ih0,
    const void* __restrict__ b_hh0, const void* __restrict__ b_ih1,
    const void* __restrict__ b_hh1, const void* __restrict__ fc_w,
    const void* __restrict__ fc_b,  const void* __restrict__ pw_ih0,
    const void* __restrict__ pb_ih0, const void* __restrict__ pb_hh0,
    const void* __restrict__ pb_ih1, const void* __restrict__ pb_hh1,
    const void* __restrict__ pfc_w, const void* __restrict__ pfc_b,
    const short* __restrict__ Whh0, const short* __restrict__ Wih1,
    const short* __restrict__ Whh1, const short* __restrict__ pWhh0,
    const short* __restrict__ pWih1, const short* __restrict__ pWhh1,
    short* H0a, short* H0b, short* H1a, short* H1b,
    int* ctr, const Hdr* __restrict__ hdr, float* __restrict__ dout)
{
  const int dt  = hdr->dtflag;
  const int tid = threadIdx.x;
  const int ug  = blockIdx.x >> 1;     // 0..127
  const int bg  = blockIdx.x & 1;      // 0..1
  const int U0  = ug * 4;
  const int B0  = bg * 128;
  int* grp = ctr + 32 + (blockIdx.x >> 5) * 32;   // 8 group ctrs, 128B apart

  __shared__ short Wl[3][64][16][8];   // 48 KB: [slot][kseg][row][8]
  __shared__ float xch[128][4][4];     // 8 KB gate exchange
  __shared__ float bs[3][16];          // [0] L0 bias, [1] L1 bias, [2] wih col
  __shared__ float obuf[128];

  const int lane = tid & 63;
  const int wv   = tid >> 6;           // m-half 0..3 (32 batches each)
  const int n    = lane & 15;          // W-row (g*4+u) AND A-row-in-tile
  const int q    = lane >> 4;
  const long abase = (long)(B0 + wv*32 + n) * 512 + q*8;

  const int eb = tid >> 1;             // epilogue batch 0..127
  const int eu = (tid & 1) * 2;        // 2 units per thread
  float c0[2] = {0.f, 0.f}, c1[2] = {0.f, 0.f};

  short *h0c = H0a, *h0n = H0b, *h1c = H1a, *h1n = H1b;
  int ph = 0;

#define STAGE(SLOT, WG)                                                      \
  for (int i = tid; i < 1024; i += 256) {                                    \
    const int r = i & 15, s_ = i >> 4;                                       \
    const int k0 = (s_ & 3) * 8 + (s_ >> 2) * 32;                            \
    const long gr = (long)((r >> 2) * 512 + U0 + (r & 3)) * 512 + k0;        \
    *(short8*)&Wl[SLOT][s_][r][0] = *(const short8*)((WG) + gr);             \
  }

#define GSEG(AP, SLOT, ACC)                                                  \
  { const short* ap_ = (AP) + abase;                                         \
    _Pragma("unroll")                                                        \
    for (int kb = 0; kb < 16; ++kb) {                                        \
      short8 b8 = *(const short8*)&Wl[SLOT][kb*4 + q][n][0];                 \
      _Pragma("unroll")                                                      \
      for (int m2 = 0; m2 < 2; ++m2) {                                       \
        short8 a8 = *(const short8*)(ap_ + (long)m2*16*512 + kb*32);         \
        ACC[m2] = __builtin_amdgcn_mfma_f32_16x16x32_bf16(a8, b8, ACC[m2], 0,0,0); \
      }                                                                      \
    } }

#define XCHW(ACC)                                                            \
  __syncthreads();                                                           \
  _Pragma("unroll")                                                          \
  for (int m2 = 0; m2 < 2; ++m2)                                             \
    _Pragma("unroll")                                                        \
    for (int r = 0; r < 4; ++r)                                              \
      xch[wv*32 + m2*16 + q*4 + r][n & 3][n >> 2] = ACC[m2][r];              \
  __syncthreads();

#define EPI(BSI, MODE, TV, CREG, HOUT)                                       \
  { float sv = 0.f;                                                          \
    if ((MODE) == 0)      sv = ldf(x, (long)(B0 + eb)*TT + (TV), dt);        \
    else if ((MODE) == 2) sv = obuf[eb];                                     \
    short2 hv;                                                               \
    _Pragma("unroll")                                                        \
    for (int j = 0; j < 2; ++j) {                                            \
      const int u = eu + j;                                                  \
      float gi = xch[eb][u][0] + bs[BSI][u];                                 \
      float gf = xch[eb][u][1] + bs[BSI][4 + u];                             \
      float gg = xch[eb][u][2] + bs[BSI][8 + u];                             \
      float go = xch[eb][u][3] + bs[BSI][12 + u];                            \
      if ((MODE) != 1) {                                                     \
        gi += sv * bs[2][u];      gf += sv * bs[2][4 + u];                   \
        gg += sv * bs[2][8 + u];  go += sv * bs[2][12 + u];                  \
      }                                                                      \
      const float I = 1.f/(1.f+expf(-gi));                                   \
      const float F = 1.f/(1.f+expf(-gf));                                   \
      const float G = tanhf(gg);                                             \
      const float O = 1.f/(1.f+expf(-go));                                   \
      const float cn = F*(CREG)[j] + I*G;                                    \
      (CREG)[j] = cn;                                                        \
      ((short*)&hv)[j] = f2bf(O * tanhf(cn));                                \
    }                                                                        \
    *(short2*)((HOUT) + (long)(B0+eb)*512 + U0 + eu) = hv;                   \
  }

#define GBAR()                                                               \
  { __syncthreads();                                                         \
    ++ph;                                                                    \
    if (tid == 0) {                                                          \
      __threadfence();                                                       \
      __hip_atomic_fetch_add(grp, 1, __ATOMIC_RELAXED,                       \
                             __HIP_MEMORY_SCOPE_AGENT);                      \
      if ((blockIdx.x & 31) == 0) {                                          \
        while (__hip_atomic_load(grp, __ATOMIC_RELAXED,                      \
                                 __HIP_MEMORY_SCOPE_AGENT) < ph * 32)        \
          __builtin_amdgcn_s_sleep(1);                                       \
        __threadfence();                                                     \
        __hip_atomic_fetch_add(ctr, 1, __ATOMIC_RELAXED,                     \
                               __HIP_MEMORY_SCOPE_AGENT);                    \
      }                                                                      \
      while (__hip_atomic_load(ctr, __ATOMIC_RELAXED,                        \
                               __HIP_MEMORY_SCOPE_AGENT) < ph * 8)           \
        __builtin_amdgcn_s_sleep(1);                                         \
      __threadfence();                                                       \
    }                                                                        \
    __syncthreads();                                                         \
  }

#define HEAD(FW, FB, S)                                                      \
  { const int hb = tid >> 1, hf = tid & 1;                                   \
    const short* hp = h1c + (long)(B0 + hb)*512 + hf*256;                    \
    float sum = 0.f;                                                         \
    for (int i = 0; i < 32; ++i) {                                           \
      short8 h8 = *(const short8*)(hp + i*8);                                \
      _Pragma("unroll")                                                      \
      for (int j = 0; j < 8; ++j)                                            \
        sum += bf2f(h8[j]) * ldf((FW), hf*256 + i*8 + j, dt);                \
    }                                                                        \
    sum += __shfl_xor(sum, 1);                                               \
    if (hf == 0) {                                                           \
      float o = sum + ldf((FB), 0, dt);                                      \
      obuf[hb] = o;                                                          \
      if (ug == 0) dout[(long)(B0 + hb)*FUT + (S)] = o;                      \
    }                                                                        \
    __syncthreads();                                                         \
  }

  // ---- one-time staging: warmup weights + biases ----
  STAGE(0, Whh0); STAGE(1, Wih1); STAGE(2, Whh1);
  if (tid < 16) {
    const long j = (long)(tid >> 2)*512 + U0 + (tid & 3);
    bs[0][tid] = ldf(b_ih0, j, dt) + ldf(b_hh0, j, dt);
    bs[1][tid] = ldf(b_ih1, j, dt) + ldf(b_hh1, j, dt);
    bs[2][tid] = ldf(w_ih0, j, dt);
  }
  __syncthreads();

  // ---- warmup: phase t = L0(t) || L1(t-1), one barrier each ----
  for (int t = 0; t < TT; ++t) {
    { floatx4 acc[2] = {{0,0,0,0},{0,0,0,0}};
      GSEG(h0c, 0, acc); XCHW(acc); }
    EPI(0, 0, t, c0, h0n);
    if (t > 0) {
      floatx4 acc[2] = {{0,0,0,0},{0,0,0,0}};
      GSEG(h0c, 1, acc); GSEG(h1c, 2, acc); XCHW(acc);
      EPI(1, 1, 0, c1, h1n);
      { short* tmp = h1c; h1c = h1n; h1n = tmp; }
    }
    { short* tmp = h0c; h0c = h0n; h0n = tmp; }
    GBAR();
  }
  // final L1(511)
  { floatx4 acc[2] = {{0,0,0,0},{0,0,0,0}};
    GSEG(h0c, 1, acc); GSEG(h1c, 2, acc); XCHW(acc);
    EPI(1, 1, 0, c1, h1n);
    { short* tmp = h1c; h1c = h1n; h1n = tmp; } }
  GBAR();
  HEAD(fc_w, fc_b, 0);

  // ---- transition: stage decode weights + biases (block-local) ----
  STAGE(0, pWhh0); STAGE(1, pWih1); STAGE(2, pWhh1);
  if (tid < 16) {
    const long j = (long)(tid >> 2)*512 + U0 + (tid & 3);
    bs[0][tid] = ldf(pb_ih0, j, dt) + ldf(pb_hh0, j, dt);
    bs[1][tid] = ldf(pb_ih1, j, dt) + ldf(pb_hh1, j, dt);
    bs[2][tid] = ldf(pw_ih0, j, dt);
  }
  __syncthreads();

  // ---- decode: 63 steps, 2 barriers each ----
  for (int s = 1; s < FUT; ++s) {
    { floatx4 acc[2] = {{0,0,0,0},{0,0,0,0}};
      GSEG(h0c, 0, acc); XCHW(acc); }
    EPI(0, 2, 0, c0, h0n);
    { short* tmp = h0c; h0c = h0n; h0n = tmp; }
    GBAR();
    { floatx4 acc[2] = {{0,0,0,0},{0,0,0,0}};
      GSEG(h0c, 1, acc); GSEG(h1c, 2, acc); XCHW(acc); }
    EPI(1, 1, 0, c1, h1n);
    { short* tmp = h1c; h1c = h1n; h1n = tmp; }
    GBAR();
    HEAD(pfc_w, pfc_b, s);
  }
#undef STAGE
#undef GSEG
#undef XCHW
#undef EPI
#undef GBAR
#undef HEAD
}

extern "C" void kernel_launch(void* const* d_in, const int* in_sizes, int n_in,
                              void* d_out, int out_size, void* d_ws, size_t ws_size,
                              hipStream_t stream) {
  float* dout = (float*)d_out;

  static const int exp_sizes[22] = {
    131072, 1, 2048, 1048576, 2048, 2048, 1048576, 1048576, 2048, 2048,
    512, 1, 2048, 1048576, 2048, 2048, 1048576, 1048576, 2048, 2048, 512, 1};
  int code = -1, m = 0;
  if (n_in != 22) { code = 0; m = n_in & 127; }
  else {
    for (int i = 0; i < 22; ++i)
      if (in_sizes[i] != exp_sizes[i]) { code = 1; m = i; break; }
  }
  if (code < 0 && out_size != BB * FUT) { code = 6; m = (out_size >> 8) & 127; }
  if (code < 0 && (d_ws == nullptr || ws_size < NEED_WS)) {
    code = 2; m = (int)(ws_size >> 20); if (m > 127) m = 127;
  }
  if (code >= 0) {
    float v = ldexpf(1.f + (float)m / 128.f, 20 + code);
    beacon_kernel<<<dim3(1), dim3(64), 0, stream>>>(dout, v);
    return;
  }

  const void* x      = d_in[0];
  const void* w_ih0  = d_in[2];
  const void* w_hh0  = d_in[3];
  const void* b_ih0  = d_in[4];
  const void* b_hh0  = d_in[5];
  const void* w_ih1  = d_in[6];
  const void* w_hh1  = d_in[7];
  const void* b_ih1  = d_in[8];
  const void* b_hh1  = d_in[9];
  const void* fc_w   = d_in[10];
  const void* fc_b   = d_in[11];
  const void* pw_ih0 = d_in[12];
  const void* pw_hh0 = d_in[13];
  const void* pb_ih0 = d_in[14];
  const void* pb_hh0 = d_in[15];
  const void* pw_ih1 = d_in[16];
  const void* pw_hh1 = d_in[17];
  const void* pb_ih1 = d_in[18];
  const void* pb_hh1 = d_in[19];
  const void* pfc_w  = d_in[20];
  const void* pfc_b  = d_in[21];

  char* ws = (char*)d_ws;
  Hdr* hdr = (Hdr*)ws;
  int* ctr = (int*)(ws + OFF_CTR);
  short* Wc[6];
  for (int i = 0; i < 6; ++i) Wc[i] = (short*)(ws + OFF_W + (size_t)i*WSZ);
  short* H0a = (short*)(ws + OFF_H);
  short* H0b = (short*)(ws + OFF_H + HSZ);
  short* H1a = (short*)(ws + OFF_H + 2*HSZ);
  short* H1b = (short*)(ws + OFF_H + 3*HSZ);

  hipMemsetAsync(ws, 0, 8192, stream);          // hdr + barrier counters
  hipMemsetAsync(H0a, 0, HSZ, stream);
  hipMemsetAsync(H1a, 0, HSZ, stream);
  probe1_kernel<<<dim3(1), dim3(256), 0, stream>>>(w_hh0, hdr);

  dim3 cg(1024), cb(256);
  cvt_kernel<<<cg, cb, 0, stream>>>(w_hh0,  Wc[0], hdr);
  cvt_kernel<<<cg, cb, 0, stream>>>(w_ih1,  Wc[1], hdr);
  cvt_kernel<<<cg, cb, 0, stream>>>(w_hh1,  Wc[2], hdr);
  cvt_kernel<<<cg, cb, 0, stream>>>(pw_hh0, Wc[3], hdr);
  cvt_kernel<<<cg, cb, 0, stream>>>(pw_ih1, Wc[4], hdr);
  cvt_kernel<<<cg, cb, 0, stream>>>(pw_hh1, Wc[5], hdr);

  lstm_persist<<<dim3(NBLK), dim3(256), 0, stream>>>(
      x, w_ih0, b_ih0, b_hh0, b_ih1, b_hh1, fc_w, fc_b,
      pw_ih0, pb_ih0, pb_hh0, pb_ih1, pb_hh1, pfc_w, pfc_b,
      Wc[0], Wc[1], Wc[2], Wc[3], Wc[4], Wc[5],
      H0a, H0b, H1a, H1b, ctr, hdr, dout);
}

// Round 11
// 14532.573 us; speedup vs baseline: 1.6256x; 1.2168x over previous
//
#include <hip/hip_runtime.h>
#include <hip/hip_bf16.h>

// Problem constants (B=256, T=512, H=512, IN=1, future=64)
#define TT  512
#define BB  256
#define HH  512
#define FUT 64
#define NBLK 256           // 128 unit-groups x 2 batch-groups

// Output dtype FP32 (r6/r7 verified). Beacons: float 2^(20+code)*(1+m/128):
//  0: n_in!=22  1: in_sizes mismatch @m  2: ws too small  6: out_size wrong
// r11: fence-free coherence — h via system-scope (sc0 sc1) atomics; no
// __threadfence anywhere => read-only data stays cached across phases.

struct Hdr { int dtflag; };

typedef __attribute__((ext_vector_type(8))) short short8;
typedef __attribute__((ext_vector_type(4))) float floatx4;

#define OFF_CTR   4096
#define OFF_W     8192
#define WSZ       ((size_t)2048*512*2)          // 2MB bf16 matrix
#define OFF_H     (OFF_W + 6*WSZ)
#define HSZ       ((size_t)BB*HH*2)             // 256KB bf16 state
#define NEED_WS   (OFF_H + 4*HSZ)               // ~13.6MB

__device__ __forceinline__ float bf2f(short s) {
  unsigned u = ((unsigned)(unsigned short)s) << 16;
  return __builtin_bit_cast(float, u);
}
__device__ __forceinline__ short f2bf(float f) {
  unsigned u = __builtin_bit_cast(unsigned, f);
  u = u + 0x7FFFu + ((u >> 16) & 1u);
  return (short)(u >> 16);
}
__device__ __forceinline__ float ldf(const void* p, long i, int dt) {
  return dt ? ((const float*)p)[i] : bf2f(((const short*)p)[i]);
}
// 16B coherence-point load (two 8B system-scope relaxed atomic loads)
__device__ __forceinline__ short8 scld16(const short* p) {
  union { short8 v; unsigned long long q[2]; } u;
  u.q[0] = __hip_atomic_load((const unsigned long long*)p,
                             __ATOMIC_RELAXED, __HIP_MEMORY_SCOPE_SYSTEM);
  u.q[1] = __hip_atomic_load((const unsigned long long*)(p + 4),
                             __ATOMIC_RELAXED, __HIP_MEMORY_SCOPE_SYSTEM);
  return u.v;
}

__global__ void beacon_kernel(float* dout, float v) {
  if (threadIdx.x == 0) dout[0] = v;
}

__global__ __launch_bounds__(256) void probe1_kernel(const void* w, Hdr* hdr) {
  const int tid = threadIdx.x;
  const short* s = (const short*)w;
  float mx = 0.f;
  #pragma unroll
  for (int i = 0; i < 16; ++i) {
    float v = fabsf(bf2f(s[tid * 16 + i]));
    if (!(v == v)) v = 1e30f;
    mx = fmaxf(mx, v);
  }
  #pragma unroll
  for (int off = 32; off > 0; off >>= 1) mx = fmaxf(mx, __shfl_down(mx, off));
  __shared__ float wmax[4];
  if ((tid & 63) == 0) wmax[tid >> 6] = mx;
  __syncthreads();
  if (tid == 0) {
    float m = fmaxf(fmaxf(wmax[0], wmax[1]), fmaxf(wmax[2], wmax[3]));
    hdr->dtflag = (m > 1000.f) ? 1 : 0;
  }
}

__global__ __launch_bounds__(256) void cvt_kernel(const void* src, short* dst,
                                                  const Hdr* hdr) {
  const int dt = hdr->dtflag;
  const long i = ((long)blockIdx.x * 256 + threadIdx.x);
  if (dt) {
    const float4 v = ((const float4*)src)[i];
    short4 o;
    o.x = f2bf(v.x); o.y = f2bf(v.y); o.z = f2bf(v.z); o.w = f2bf(v.w);
    ((short4*)dst)[i] = o;
  } else {
    ((short4*)dst)[i] = ((const short4*)src)[i];
  }
}

// Persistent 2-layer LSTM, LDS-resident weights, fence-free sc coherence.
// 256 blocks = 128 ug x 2 bg. Block owns 4 units x 128 batches.
__global__ __launch_bounds__(256) void lstm_persist(
    const void* __restrict__ x,
    const void* __restrict__ w_ih0, const void* __restrict__ b_ih0,
    const void* __restrict__ b_hh0, const void* __restrict__ b_ih1,
    const void* __restrict__ b_hh1, const void* __restrict__ fc_w,
    const void* __restrict__ fc_b,  const void* __restrict__ pw_ih0,
    const void* __restrict__ pb_ih0, const void* __restrict__ pb_hh0,
    const void* __restrict__ pb_ih1, const void* __restrict__ pb_hh1,
    const void* __restrict__ pfc_w, const void* __restrict__ pfc_b,
    const short* __restrict__ Whh0, const short* __restrict__ Wih1,
    const short* __restrict__ Whh1, const short* __restrict__ pWhh0,
    const short* __restrict__ pWih1, const short* __restrict__ pWhh1,
    short* H0a, short* H0b, short* H1a, short* H1b,
    int* ctr, const Hdr* __restrict__ hdr, float* __restrict__ dout)
{
  const int dt  = hdr->dtflag;
  const int tid = threadIdx.x;
  const int ug  = blockIdx.x >> 1;     // 0..127
  const int bg  = blockIdx.x & 1;      // 0..1
  const int U0  = ug * 4;
  const int B0  = bg * 128;
  int* grp = ctr + 32 + (blockIdx.x >> 5) * 32;   // 8 group ctrs, 128B apart

  __shared__ short Wl[3][64][16][8];   // 48 KB: [slot][kseg][row][8]
  __shared__ float xch[128][4][4];     // 8 KB gate exchange
  __shared__ float bs[3][16];          // [0] L0 bias, [1] L1 bias, [2] wih col
  __shared__ float obuf[128];

  const int lane = tid & 63;
  const int wv   = tid >> 6;           // m-half 0..3 (32 batches each)
  const int n    = lane & 15;
  const int q    = lane >> 4;
  const long abase = (long)(B0 + wv*32 + n) * 512 + q*8;

  const int eb = tid >> 1;             // epilogue batch 0..127
  const int eu = (tid & 1) * 2;        // 2 units per thread
  float c0[2] = {0.f, 0.f}, c1[2] = {0.f, 0.f};

  short *h0c = H0a, *h0n = H0b, *h1c = H1a, *h1n = H1b;
  int ph = 0;

#define STAGE(SLOT, WG)                                                      \
  for (int i = tid; i < 1024; i += 256) {                                    \
    const int r = i & 15, s_ = i >> 4;                                       \
    const int k0 = (s_ & 3) * 8 + (s_ >> 2) * 32;                            \
    const long gr = (long)((r >> 2) * 512 + U0 + (r & 3)) * 512 + k0;        \
    *(short8*)&Wl[SLOT][s_][r][0] = *(const short8*)((WG) + gr);             \
  }

// fused: one sc pass over AP feeding two accumulator sets (slots S0,S1)
#define GSEG2(AP, S0, S1, A0, A1, DUAL)                                      \
  { const short* ap_ = (AP) + abase;                                         \
    _Pragma("unroll")                                                        \
    for (int kb = 0; kb < 16; ++kb) {                                        \
      short8 b80 = *(const short8*)&Wl[S0][kb*4 + q][n][0];                  \
      short8 b81 = *(const short8*)&Wl[S1][kb*4 + q][n][0];                  \
      _Pragma("unroll")                                                      \
      for (int m2 = 0; m2 < 2; ++m2) {                                       \
        short8 a8 = scld16(ap_ + (long)m2*16*512 + kb*32);                   \
        A0[m2] = __builtin_amdgcn_mfma_f32_16x16x32_bf16(a8, b80, A0[m2], 0,0,0); \
        if (DUAL)                                                            \
          A1[m2] = __builtin_amdgcn_mfma_f32_16x16x32_bf16(a8, b81, A1[m2], 0,0,0); \
      }                                                                      \
    } }

#define GSEG1(AP, SLOT, ACC)                                                 \
  { const short* ap_ = (AP) + abase;                                         \
    _Pragma("unroll")                                                        \
    for (int kb = 0; kb < 16; ++kb) {                                        \
      short8 b8 = *(const short8*)&Wl[SLOT][kb*4 + q][n][0];                 \
      _Pragma("unroll")                                                      \
      for (int m2 = 0; m2 < 2; ++m2) {                                       \
        short8 a8 = scld16(ap_ + (long)m2*16*512 + kb*32);                   \
        ACC[m2] = __builtin_amdgcn_mfma_f32_16x16x32_bf16(a8, b8, ACC[m2], 0,0,0); \
      }                                                                      \
    } }

#define XCHW(ACC)                                                            \
  __syncthreads();                                                           \
  _Pragma("unroll")                                                          \
  for (int m2 = 0; m2 < 2; ++m2)                                             \
    _Pragma("unroll")                                                        \
    for (int r = 0; r < 4; ++r)                                              \
      xch[wv*32 + m2*16 + q*4 + r][n & 3][n >> 2] = ACC[m2][r];              \
  __syncthreads();

#define EPI(BSI, MODE, TV, CREG, HOUT)                                       \
  { float sv = 0.f;                                                          \
    if ((MODE) == 0)      sv = ldf(x, (long)(B0 + eb)*TT + (TV), dt);        \
    else if ((MODE) == 2) sv = obuf[eb];                                     \
    short2 hv;                                                               \
    _Pragma("unroll")                                                        \
    for (int j = 0; j < 2; ++j) {                                            \
      const int u = eu + j;                                                  \
      float gi = xch[eb][u][0] + bs[BSI][u];                                 \
      float gf = xch[eb][u][1] + bs[BSI][4 + u];                             \
      float gg = xch[eb][u][2] + bs[BSI][8 + u];                             \
      float go = xch[eb][u][3] + bs[BSI][12 + u];                            \
      if ((MODE) != 1) {                                                     \
        gi += sv * bs[2][u];      gf += sv * bs[2][4 + u];                   \
        gg += sv * bs[2][8 + u];  go += sv * bs[2][12 + u];                  \
      }                                                                      \
      const float I = 1.f/(1.f+expf(-gi));                                   \
      const float F = 1.f/(1.f+expf(-gf));                                   \
      const float G = tanhf(gg);                                             \
      const float O = 1.f/(1.f+expf(-go));                                   \
      const float cn = F*(CREG)[j] + I*G;                                    \
      (CREG)[j] = cn;                                                        \
      ((short*)&hv)[j] = f2bf(O * tanhf(cn));                                \
    }                                                                        \
    __hip_atomic_store((int*)((HOUT) + (long)(B0+eb)*512 + U0 + eu),         \
                       *(int*)&hv, __ATOMIC_RELAXED,                         \
                       __HIP_MEMORY_SCOPE_SYSTEM);                           \
  }

// fence-free barrier: release = s_waitcnt vmcnt(0) + relaxed add;
// acquire = relaxed poll (h travels via sc ops, caches never flushed)
#define GBAR()                                                               \
  { __syncthreads();                                                         \
    ++ph;                                                                    \
    if (tid == 0) {                                                          \
      asm volatile("s_waitcnt vmcnt(0)" ::: "memory");                       \
      __hip_atomic_fetch_add(grp, 1, __ATOMIC_RELAXED,                       \
                             __HIP_MEMORY_SCOPE_SYSTEM);                     \
      if ((blockIdx.x & 31) == 0) {                                          \
        while (__hip_atomic_load(grp, __ATOMIC_RELAXED,                      \
                                 __HIP_MEMORY_SCOPE_SYSTEM) < ph * 32)       \
          __builtin_amdgcn_s_sleep(1);                                       \
        __hip_atomic_fetch_add(ctr, 1, __ATOMIC_RELAXED,                     \
                               __HIP_MEMORY_SCOPE_SYSTEM);                   \
      }                                                                      \
      while (__hip_atomic_load(ctr, __ATOMIC_RELAXED,                        \
                               __HIP_MEMORY_SCOPE_SYSTEM) < ph * 8)          \
        __builtin_amdgcn_s_sleep(1);                                         \
    }                                                                        \
    __syncthreads();                                                         \
  }

#define HEAD(H1C, FW, FB, S)                                                 \
  { const int hb = tid >> 1, hf = tid & 1;                                   \
    const short* hp = (H1C) + (long)(B0 + hb)*512 + hf*256;                  \
    float sum = 0.f;                                                         \
    for (int i = 0; i < 32; ++i) {                                           \
      short8 h8 = scld16(hp + i*8);                                          \
      _Pragma("unroll")                                                      \
      for (int j = 0; j < 8; ++j)                                            \
        sum += bf2f(h8[j]) * ldf((FW), hf*256 + i*8 + j, dt);                \
    }                                                                        \
    sum += __shfl_xor(sum, 1);                                               \
    if (hf == 0) {                                                           \
      float o = sum + ldf((FB), 0, dt);                                      \
      obuf[hb] = o;                                                          \
      if (ug == 0) dout[(long)(B0 + hb)*FUT + (S)] = o;                      \
    }                                                                        \
    __syncthreads();                                                         \
  }

  // ---- one-time staging: warmup weights + biases ----
  STAGE(0, Whh0); STAGE(1, Wih1); STAGE(2, Whh1);
  if (tid < 16) {
    const long j = (long)(tid >> 2)*512 + U0 + (tid & 3);
    bs[0][tid] = ldf(b_ih0, j, dt) + ldf(b_hh0, j, dt);
    bs[1][tid] = ldf(b_ih1, j, dt) + ldf(b_hh1, j, dt);
    bs[2][tid] = ldf(w_ih0, j, dt);
  }
  __syncthreads();

  // ---- warmup: phase t = L0(t) || L1(t-1), one barrier each ----
  for (int t = 0; t < TT; ++t) {
    floatx4 a0[2] = {{0,0,0,0},{0,0,0,0}};
    floatx4 a1[2] = {{0,0,0,0},{0,0,0,0}};
    GSEG2(h0c, 0, 1, a0, a1, (t > 0));   // one h0 pass feeds Whh0 + Wih1
    XCHW(a0);
    EPI(0, 0, t, c0, h0n);
    if (t > 0) {
      GSEG1(h1c, 2, a1);
      XCHW(a1);
      EPI(1, 1, 0, c1, h1n);
      { short* tmp = h1c; h1c = h1n; h1n = tmp; }
    }
    { short* tmp = h0c; h0c = h0n; h0n = tmp; }
    GBAR();
  }
  // final L1(511)
  { floatx4 a1[2] = {{0,0,0,0},{0,0,0,0}};
    GSEG1(h0c, 1, a1); GSEG1(h1c, 2, a1); XCHW(a1);
    EPI(1, 1, 0, c1, h1n);
    { short* tmp = h1c; h1c = h1n; h1n = tmp; } }
  GBAR();
  HEAD(h1c, fc_w, fc_b, 0);

  // ---- transition: stage decode weights + biases (block-local) ----
  STAGE(0, pWhh0); STAGE(1, pWih1); STAGE(2, pWhh1);
  if (tid < 16) {
    const long j = (long)(tid >> 2)*512 + U0 + (tid & 3);
    bs[0][tid] = ldf(pb_ih0, j, dt) + ldf(pb_hh0, j, dt);
    bs[1][tid] = ldf(pb_ih1, j, dt) + ldf(pb_hh1, j, dt);
    bs[2][tid] = ldf(pw_ih0, j, dt);
  }
  __syncthreads();

  // ---- decode: 63 steps, 2 barriers each ----
  for (int s = 1; s < FUT; ++s) {
    { floatx4 a0[2] = {{0,0,0,0},{0,0,0,0}};
      GSEG1(h0c, 0, a0); XCHW(a0); }
    EPI(0, 2, 0, c0, h0n);
    { short* tmp = h0c; h0c = h0n; h0n = tmp; }
    GBAR();
    { floatx4 a1[2] = {{0,0,0,0},{0,0,0,0}};
      GSEG1(h0c, 1, a1); GSEG1(h1c, 2, a1); XCHW(a1);
      EPI(1, 1, 0, c1, h1n); }
    { short* tmp = h1c; h1c = h1n; h1n = tmp; }
    GBAR();
    HEAD(h1c, pfc_w, pfc_b, s);
  }
#undef STAGE
#undef GSEG2
#undef GSEG1
#undef XCHW
#undef EPI
#undef GBAR
#undef HEAD
}

extern "C" void kernel_launch(void* const* d_in, const int* in_sizes, int n_in,
                              void* d_out, int out_size, void* d_ws, size_t ws_size,
                              hipStream_t stream) {
  float* dout = (float*)d_out;

  static const int exp_sizes[22] = {
    131072, 1, 2048, 1048576, 2048, 2048, 1048576, 1048576, 2048, 2048,
    512, 1, 2048, 1048576, 2048, 2048, 1048576, 1048576, 2048, 2048, 512, 1};
  int code = -1, m = 0;
  if (n_in != 22) { code = 0; m = n_in & 127; }
  else {
    for (int i = 0; i < 22; ++i)
      if (in_sizes[i] != exp_sizes[i]) { code = 1; m = i; break; }
  }
  if (code < 0 && out_size != BB * FUT) { code = 6; m = (out_size >> 8) & 127; }
  if (code < 0 && (d_ws == nullptr || ws_size < NEED_WS)) {
    code = 2; m = (int)(ws_size >> 20); if (m > 127) m = 127;
  }
  if (code >= 0) {
    float v = ldexpf(1.f + (float)m / 128.f, 20 + code);
    beacon_kernel<<<dim3(1), dim3(64), 0, stream>>>(dout, v);
    return;
  }

  const void* x      = d_in[0];
  const void* w_ih0  = d_in[2];
  const void* w_hh0  = d_in[3];
  const void* b_ih0  = d_in[4];
  const void* b_hh0  = d_in[5];
  const void* w_ih1  = d_in[6];
  const void* w_hh1  = d_in[7];
  const void* b_ih1  = d_in[8];
  const void* b_hh1  = d_in[9];
  const void* fc_w   = d_in[10];
  const void* fc_b   = d_in[11];
  const void* pw_ih0 = d_in[12];
  const void* pw_hh0 = d_in[13];
  const void* pb_ih0 = d_in[14];
  const void* pb_hh0 = d_in[15];
  const void* pw_ih1 = d_in[16];
  const void* pw_hh1 = d_in[17];
  const void* pb_ih1 = d_in[18];
  const void* pb_hh1 = d_in[19];
  const void* pfc_w  = d_in[20];
  const void* pfc_b  = d_in[21];

  char* ws = (char*)d_ws;
  Hdr* hdr = (Hdr*)ws;
  int* ctr = (int*)(ws + OFF_CTR);
  short* Wc[6];
  for (int i = 0; i < 6; ++i) Wc[i] = (short*)(ws + OFF_W + (size_t)i*WSZ);
  short* H0a = (short*)(ws + OFF_H);
  short* H0b = (short*)(ws + OFF_H + HSZ);
  short* H1a = (short*)(ws + OFF_H + 2*HSZ);
  short* H1b = (short*)(ws + OFF_H + 3*HSZ);

  hipMemsetAsync(ws, 0, 8192, stream);          // hdr + barrier counters
  hipMemsetAsync(H0a, 0, HSZ, stream);
  hipMemsetAsync(H1a, 0, HSZ, stream);
  probe1_kernel<<<dim3(1), dim3(256), 0, stream>>>(w_hh0, hdr);

  dim3 cg(1024), cb(256);
  cvt_kernel<<<cg, cb, 0, stream>>>(w_hh0,  Wc[0], hdr);
  cvt_kernel<<<cg, cb, 0, stream>>>(w_ih1,  Wc[1], hdr);
  cvt_kernel<<<cg, cb, 0, stream>>>(w_hh1,  Wc[2], hdr);
  cvt_kernel<<<cg, cb, 0, stream>>>(pw_hh0, Wc[3], hdr);
  cvt_kernel<<<cg, cb, 0, stream>>>(pw_ih1, Wc[4], hdr);
  cvt_kernel<<<cg, cb, 0, stream>>>(pw_hh1, Wc[5], hdr);

  lstm_persist<<<dim3(NBLK), dim3(256), 0, stream>>>(
      x, w_ih0, b_ih0, b_hh0, b_ih1, b_hh1, fc_w, fc_b,
      pw_ih0, pb_ih0, pb_hh0, pb_ih1, pb_hh1, pfc_w, pfc_b,
      Wc[0], Wc[1], Wc[2], Wc[3], Wc[4], Wc[5],
      H0a, H0b, H1a, H1b, ctr, hdr, dout);
}

// Round 12
// 13533.875 us; speedup vs baseline: 1.7456x; 1.0738x over previous
//
#include <hip/hip_runtime.h>
#include <hip/hip_bf16.h>

// Problem constants (B=256, T=512, H=512, IN=1, future=64)
#define TT  512
#define BB  256
#define HH  512
#define FUT 64
#define NBLK 256           // 128 unit-groups x 2 batch-groups

// Output dtype FP32 (r6/r7 verified). Beacons: float 2^(20+code)*(1+m/128):
//  0: n_in!=22  1: in_sizes mismatch @m  2: ws too small  6: out_size wrong
// r12: software-pipelined sc loads (double-buffered 8-frag groups) + grouped
// HEAD prefetch + per-group barrier release lines. Coherence scheme = r11
// (fence-free, h via system-scope atomics; caches never flushed).

struct Hdr { int dtflag; };

typedef __attribute__((ext_vector_type(8))) short short8;
typedef __attribute__((ext_vector_type(4))) float floatx4;

#define OFF_CTR   4096
#define OFF_W     8192
#define WSZ       ((size_t)2048*512*2)          // 2MB bf16 matrix
#define OFF_H     (OFF_W + 6*WSZ)
#define HSZ       ((size_t)BB*HH*2)             // 256KB bf16 state
#define NEED_WS   (OFF_H + 4*HSZ)               // ~13.6MB

__device__ __forceinline__ float bf2f(short s) {
  unsigned u = ((unsigned)(unsigned short)s) << 16;
  return __builtin_bit_cast(float, u);
}
__device__ __forceinline__ short f2bf(float f) {
  unsigned u = __builtin_bit_cast(unsigned, f);
  u = u + 0x7FFFu + ((u >> 16) & 1u);
  return (short)(u >> 16);
}
__device__ __forceinline__ float ldf(const void* p, long i, int dt) {
  return dt ? ((const float*)p)[i] : bf2f(((const short*)p)[i]);
}
// 16B coherence-point load (two 8B system-scope relaxed atomic loads)
__device__ __forceinline__ short8 scld16(const short* p) {
  union { short8 v; unsigned long long q[2]; } u;
  u.q[0] = __hip_atomic_load((const unsigned long long*)p,
                             __ATOMIC_RELAXED, __HIP_MEMORY_SCOPE_SYSTEM);
  u.q[1] = __hip_atomic_load((const unsigned long long*)(p + 4),
                             __ATOMIC_RELAXED, __HIP_MEMORY_SCOPE_SYSTEM);
  return u.v;
}

__global__ void beacon_kernel(float* dout, float v) {
  if (threadIdx.x == 0) dout[0] = v;
}

__global__ __launch_bounds__(256) void probe1_kernel(const void* w, Hdr* hdr) {
  const int tid = threadIdx.x;
  const short* s = (const short*)w;
  float mx = 0.f;
  #pragma unroll
  for (int i = 0; i < 16; ++i) {
    float v = fabsf(bf2f(s[tid * 16 + i]));
    if (!(v == v)) v = 1e30f;
    mx = fmaxf(mx, v);
  }
  #pragma unroll
  for (int off = 32; off > 0; off >>= 1) mx = fmaxf(mx, __shfl_down(mx, off));
  __shared__ float wmax[4];
  if ((tid & 63) == 0) wmax[tid >> 6] = mx;
  __syncthreads();
  if (tid == 0) {
    float m = fmaxf(fmaxf(wmax[0], wmax[1]), fmaxf(wmax[2], wmax[3]));
    hdr->dtflag = (m > 1000.f) ? 1 : 0;
  }
}

__global__ __launch_bounds__(256) void cvt_kernel(const void* src, short* dst,
                                                  const Hdr* hdr) {
  const int dt = hdr->dtflag;
  const long i = ((long)blockIdx.x * 256 + threadIdx.x);
  if (dt) {
    const float4 v = ((const float4*)src)[i];
    short4 o;
    o.x = f2bf(v.x); o.y = f2bf(v.y); o.z = f2bf(v.z); o.w = f2bf(v.w);
    ((short4*)dst)[i] = o;
  } else {
    ((short4*)dst)[i] = ((const short4*)src)[i];
  }
}

// Persistent 2-layer LSTM, LDS weights, fence-free sc coherence, pipelined.
__global__ __launch_bounds__(256) void lstm_persist(
    const void* __restrict__ x,
    const void* __restrict__ w_ih0, const void* __restrict__ b_ih0,
    const void* __restrict__ b_hh0, const void* __restrict__ b_ih1,
    const void* __restrict__ b_hh1, const void* __restrict__ fc_w,
    const void* __restrict__ fc_b,  const void* __restrict__ pw_ih0,
    const void* __restrict__ pb_ih0, const void* __restrict__ pb_hh0,
    const void* __restrict__ pb_ih1, const void* __restrict__ pb_hh1,
    const void* __restrict__ pfc_w, const void* __restrict__ pfc_b,
    const short* __restrict__ Whh0, const short* __restrict__ Wih1,
    const short* __restrict__ Whh1, const short* __restrict__ pWhh0,
    const short* __restrict__ pWih1, const short* __restrict__ pWhh1,
    short* H0a, short* H0b, short* H1a, short* H1b,
    int* ctr, const Hdr* __restrict__ hdr, float* __restrict__ dout)
{
  const int dt  = hdr->dtflag;
  const int tid = threadIdx.x;
  const int ug  = blockIdx.x >> 1;     // 0..127
  const int bg  = blockIdx.x & 1;      // 0..1
  const int U0  = ug * 4;
  const int B0  = bg * 128;
  int* grpArr = ctr + 32 + (blockIdx.x >> 5) * 32;        // arrive line
  int* grpRel = ctr + 32 + (blockIdx.x >> 5) * 32 + 16;   // release line
  const int isMaster = (blockIdx.x & 31) == 0;

  __shared__ short Wl[3][64][16][8];   // 48 KB: [slot][kseg][row][8]
  __shared__ float xch[128][4][4];     // 8 KB gate exchange
  __shared__ float bs[3][16];          // [0] L0 bias, [1] L1 bias, [2] wih col
  __shared__ float obuf[128];

  const int lane = tid & 63;
  const int wv   = tid >> 6;           // m-half 0..3 (32 batches each)
  const int n    = lane & 15;
  const int q    = lane >> 4;
  const long abase = (long)(B0 + wv*32 + n) * 512 + q*8;

  const int eb = tid >> 1;             // epilogue batch 0..127
  const int eu = (tid & 1) * 2;        // 2 units per thread
  float c0[2] = {0.f, 0.f}, c1[2] = {0.f, 0.f};

  short *h0c = H0a, *h0n = H0b, *h1c = H1a, *h1n = H1b;
  int ph = 0;

#define STAGE(SLOT, WG)                                                      \
  for (int i = tid; i < 1024; i += 256) {                                    \
    const int r = i & 15, s_ = i >> 4;                                       \
    const int k0 = (s_ & 3) * 8 + (s_ >> 2) * 32;                            \
    const long gr = (long)((r >> 2) * 512 + U0 + (r & 3)) * 512 + k0;        \
    *(short8*)&Wl[SLOT][s_][r][0] = *(const short8*)((WG) + gr);             \
  }

// flat idx 0..31: m2 = idx>>4, kb = idx&15. A-offset + W-row helpers.
#define AOFF(IDX) ((long)((IDX) >> 4) * 16 * 512 + ((IDX) & 15) * 32)
#define WROW(IDX) (((IDX) & 15) * 4 + q)

// pipelined single-W pass: 4 groups of 8, double-buffered prefetch
#define GSEG1(AP, SLOT, ACC)                                                 \
  { const short* ap_ = (AP) + abase;                                         \
    short8 abuf[2][8];                                                       \
    _Pragma("unroll")                                                        \
    for (int i = 0; i < 8; ++i) abuf[0][i] = scld16(ap_ + AOFF(i));          \
    _Pragma("unroll")                                                        \
    for (int g = 0; g < 4; ++g) {                                            \
      if (g < 3) {                                                           \
        _Pragma("unroll")                                                    \
        for (int i = 0; i < 8; ++i)                                          \
          abuf[(g + 1) & 1][i] = scld16(ap_ + AOFF((g + 1) * 8 + i));        \
      }                                                                      \
      _Pragma("unroll")                                                      \
      for (int i = 0; i < 8; ++i) {                                          \
        const int idx = g * 8 + i;                                           \
        short8 b8 = *(const short8*)&Wl[SLOT][WROW(idx)][n][0];              \
        ACC[idx >> 4] = __builtin_amdgcn_mfma_f32_16x16x32_bf16(             \
            abuf[g & 1][i], b8, ACC[idx >> 4], 0, 0, 0);                     \
      }                                                                      \
    } }

// pipelined dual-W pass (one h stream feeds two weight slots)
#define GSEG2(AP, S0, S1, A0, A1, DUAL)                                      \
  { const short* ap_ = (AP) + abase;                                         \
    short8 abuf[2][8];                                                       \
    _Pragma("unroll")                                                        \
    for (int i = 0; i < 8; ++i) abuf[0][i] = scld16(ap_ + AOFF(i));          \
    _Pragma("unroll")                                                        \
    for (int g = 0; g < 4; ++g) {                                            \
      if (g < 3) {                                                           \
        _Pragma("unroll")                                                    \
        for (int i = 0; i < 8; ++i)                                          \
          abuf[(g + 1) & 1][i] = scld16(ap_ + AOFF((g + 1) * 8 + i));        \
      }                                                                      \
      _Pragma("unroll")                                                      \
      for (int i = 0; i < 8; ++i) {                                          \
        const int idx = g * 8 + i;                                           \
        short8 b80 = *(const short8*)&Wl[S0][WROW(idx)][n][0];               \
        A0[idx >> 4] = __builtin_amdgcn_mfma_f32_16x16x32_bf16(              \
            abuf[g & 1][i], b80, A0[idx >> 4], 0, 0, 0);                     \
        if (DUAL) {                                                          \
          short8 b81 = *(const short8*)&Wl[S1][WROW(idx)][n][0];             \
          A1[idx >> 4] = __builtin_amdgcn_mfma_f32_16x16x32_bf16(            \
              abuf[g & 1][i], b81, A1[idx >> 4], 0, 0, 0);                   \
        }                                                                    \
      }                                                                      \
    } }

#define XCHW(ACC)                                                            \
  __syncthreads();                                                           \
  _Pragma("unroll")                                                          \
  for (int m2 = 0; m2 < 2; ++m2)                                             \
    _Pragma("unroll")                                                        \
    for (int r = 0; r < 4; ++r)                                              \
      xch[wv*32 + m2*16 + q*4 + r][n & 3][n >> 2] = ACC[m2][r];              \
  __syncthreads();

#define EPI(BSI, MODE, TV, CREG, HOUT)                                       \
  { float sv = 0.f;                                                          \
    if ((MODE) == 0)      sv = ldf(x, (long)(B0 + eb)*TT + (TV), dt);        \
    else if ((MODE) == 2) sv = obuf[eb];                                     \
    short2 hv;                                                               \
    _Pragma("unroll")                                                        \
    for (int j = 0; j < 2; ++j) {                                            \
      const int u = eu + j;                                                  \
      float gi = xch[eb][u][0] + bs[BSI][u];                                 \
      float gf = xch[eb][u][1] + bs[BSI][4 + u];                             \
      float gg = xch[eb][u][2] + bs[BSI][8 + u];                             \
      float go = xch[eb][u][3] + bs[BSI][12 + u];                            \
      if ((MODE) != 1) {                                                     \
        gi += sv * bs[2][u];      gf += sv * bs[2][4 + u];                   \
        gg += sv * bs[2][8 + u];  go += sv * bs[2][12 + u];                  \
      }                                                                      \
      const float I = 1.f/(1.f+expf(-gi));                                   \
      const float F = 1.f/(1.f+expf(-gf));                                   \
      const float G = tanhf(gg);                                             \
      const float O = 1.f/(1.f+expf(-go));                                   \
      const float cn = F*(CREG)[j] + I*G;                                    \
      (CREG)[j] = cn;                                                        \
      ((short*)&hv)[j] = f2bf(O * tanhf(cn));                                \
    }                                                                        \
    __hip_atomic_store((int*)((HOUT) + (long)(B0+eb)*512 + U0 + eu),         \
                       *(int*)&hv, __ATOMIC_RELAXED,                         \
                       __HIP_MEMORY_SCOPE_SYSTEM);                           \
  }

// fence-free barrier, per-group release line
#define GBAR()                                                               \
  { __syncthreads();                                                         \
    ++ph;                                                                    \
    if (tid == 0) {                                                          \
      asm volatile("s_waitcnt vmcnt(0)" ::: "memory");                       \
      __hip_atomic_fetch_add(grpArr, 1, __ATOMIC_RELAXED,                    \
                             __HIP_MEMORY_SCOPE_SYSTEM);                     \
      if (isMaster) {                                                        \
        while (__hip_atomic_load(grpArr, __ATOMIC_RELAXED,                   \
                                 __HIP_MEMORY_SCOPE_SYSTEM) < ph * 32)       \
          __builtin_amdgcn_s_sleep(1);                                       \
        __hip_atomic_fetch_add(ctr, 1, __ATOMIC_RELAXED,                     \
                               __HIP_MEMORY_SCOPE_SYSTEM);                   \
        while (__hip_atomic_load(ctr, __ATOMIC_RELAXED,                      \
                                 __HIP_MEMORY_SCOPE_SYSTEM) < ph * 8)        \
          __builtin_amdgcn_s_sleep(1);                                       \
        __hip_atomic_store(grpRel, ph, __ATOMIC_RELAXED,                     \
                           __HIP_MEMORY_SCOPE_SYSTEM);                       \
      } else {                                                               \
        while (__hip_atomic_load(grpRel, __ATOMIC_RELAXED,                   \
                                 __HIP_MEMORY_SCOPE_SYSTEM) < ph)            \
          __builtin_amdgcn_s_sleep(1);                                       \
      }                                                                      \
    }                                                                        \
    __syncthreads();                                                         \
  }

#define HEAD(H1C, FW, FB, S)                                                 \
  { const int hb = tid >> 1, hf = tid & 1;                                   \
    const short* hp = (H1C) + (long)(B0 + hb)*512 + hf*256;                  \
    float sum = 0.f;                                                         \
    for (int g4 = 0; g4 < 4; ++g4) {                                         \
      short8 habuf[8];                                                       \
      _Pragma("unroll")                                                      \
      for (int i = 0; i < 8; ++i) habuf[i] = scld16(hp + (g4*8 + i)*8);      \
      _Pragma("unroll")                                                      \
      for (int i = 0; i < 8; ++i)                                            \
        _Pragma("unroll")                                                    \
        for (int j = 0; j < 8; ++j)                                          \
          sum += bf2f(habuf[i][j]) * ldf((FW), hf*256 + (g4*8+i)*8 + j, dt); \
    }                                                                        \
    sum += __shfl_xor(sum, 1);                                               \
    if (hf == 0) {                                                           \
      float o = sum + ldf((FB), 0, dt);                                      \
      obuf[hb] = o;                                                          \
      if (ug == 0) dout[(long)(B0 + hb)*FUT + (S)] = o;                      \
    }                                                                        \
    __syncthreads();                                                         \
  }

  // ---- one-time staging: warmup weights + biases ----
  STAGE(0, Whh0); STAGE(1, Wih1); STAGE(2, Whh1);
  if (tid < 16) {
    const long j = (long)(tid >> 2)*512 + U0 + (tid & 3);
    bs[0][tid] = ldf(b_ih0, j, dt) + ldf(b_hh0, j, dt);
    bs[1][tid] = ldf(b_ih1, j, dt) + ldf(b_hh1, j, dt);
    bs[2][tid] = ldf(w_ih0, j, dt);
  }
  __syncthreads();

  // ---- warmup: phase t = L0(t) || L1(t-1), one barrier each ----
  for (int t = 0; t < TT; ++t) {
    floatx4 a0[2] = {{0,0,0,0},{0,0,0,0}};
    floatx4 a1[2] = {{0,0,0,0},{0,0,0,0}};
    GSEG2(h0c, 0, 1, a0, a1, (t > 0));   // one h0 pass feeds Whh0 + Wih1
    XCHW(a0);
    EPI(0, 0, t, c0, h0n);
    if (t > 0) {
      GSEG1(h1c, 2, a1);
      XCHW(a1);
      EPI(1, 1, 0, c1, h1n);
      { short* tmp = h1c; h1c = h1n; h1n = tmp; }
    }
    { short* tmp = h0c; h0c = h0n; h0n = tmp; }
    GBAR();
  }
  // final L1(511)
  { floatx4 a1[2] = {{0,0,0,0},{0,0,0,0}};
    GSEG1(h0c, 1, a1); GSEG1(h1c, 2, a1); XCHW(a1);
    EPI(1, 1, 0, c1, h1n);
    { short* tmp = h1c; h1c = h1n; h1n = tmp; } }
  GBAR();
  HEAD(h1c, fc_w, fc_b, 0);

  // ---- transition: stage decode weights + biases (block-local) ----
  STAGE(0, pWhh0); STAGE(1, pWih1); STAGE(2, pWhh1);
  if (tid < 16) {
    const long j = (long)(tid >> 2)*512 + U0 + (tid & 3);
    bs[0][tid] = ldf(pb_ih0, j, dt) + ldf(pb_hh0, j, dt);
    bs[1][tid] = ldf(pb_ih1, j, dt) + ldf(pb_hh1, j, dt);
    bs[2][tid] = ldf(pw_ih0, j, dt);
  }
  __syncthreads();

  // ---- decode: 63 steps, 2 barriers each ----
  for (int s = 1; s < FUT; ++s) {
    { floatx4 a0[2] = {{0,0,0,0},{0,0,0,0}};
      GSEG1(h0c, 0, a0); XCHW(a0); }
    EPI(0, 2, 0, c0, h0n);
    { short* tmp = h0c; h0c = h0n; h0n = tmp; }
    GBAR();
    { floatx4 a1[2] = {{0,0,0,0},{0,0,0,0}};
      GSEG1(h0c, 1, a1); GSEG1(h1c, 2, a1); XCHW(a1);
      EPI(1, 1, 0, c1, h1n); }
    { short* tmp = h1c; h1c = h1n; h1n = tmp; }
    GBAR();
    HEAD(h1c, pfc_w, pfc_b, s);
  }
#undef STAGE
#undef GSEG2
#undef GSEG1
#undef XCHW
#undef EPI
#undef GBAR
#undef HEAD
#undef AOFF
#undef WROW
}

extern "C" void kernel_launch(void* const* d_in, const int* in_sizes, int n_in,
                              void* d_out, int out_size, void* d_ws, size_t ws_size,
                              hipStream_t stream) {
  float* dout = (float*)d_out;

  static const int exp_sizes[22] = {
    131072, 1, 2048, 1048576, 2048, 2048, 1048576, 1048576, 2048, 2048,
    512, 1, 2048, 1048576, 2048, 2048, 1048576, 1048576, 2048, 2048, 512, 1};
  int code = -1, m = 0;
  if (n_in != 22) { code = 0; m = n_in & 127; }
  else {
    for (int i = 0; i < 22; ++i)
      if (in_sizes[i] != exp_sizes[i]) { code = 1; m = i; break; }
  }
  if (code < 0 && out_size != BB * FUT) { code = 6; m = (out_size >> 8) & 127; }
  if (code < 0 && (d_ws == nullptr || ws_size < NEED_WS)) {
    code = 2; m = (int)(ws_size >> 20); if (m > 127) m = 127;
  }
  if (code >= 0) {
    float v = ldexpf(1.f + (float)m / 128.f, 20 + code);
    beacon_kernel<<<dim3(1), dim3(64), 0, stream>>>(dout, v);
    return;
  }

  const void* x      = d_in[0];
  const void* w_ih0  = d_in[2];
  const void* w_hh0  = d_in[3];
  const void* b_ih0  = d_in[4];
  const void* b_hh0  = d_in[5];
  const void* w_ih1  = d_in[6];
  const void* w_hh1  = d_in[7];
  const void* b_ih1  = d_in[8];
  const void* b_hh1  = d_in[9];
  const void* fc_w   = d_in[10];
  const void* fc_b   = d_in[11];
  const void* pw_ih0 = d_in[12];
  const void* pw_hh0 = d_in[13];
  const void* pb_ih0 = d_in[14];
  const void* pb_hh0 = d_in[15];
  const void* pw_ih1 = d_in[16];
  const void* pw_hh1 = d_in[17];
  const void* pb_ih1 = d_in[18];
  const void* pb_hh1 = d_in[19];
  const void* pfc_w  = d_in[20];
  const void* pfc_b  = d_in[21];

  char* ws = (char*)d_ws;
  Hdr* hdr = (Hdr*)ws;
  int* ctr = (int*)(ws + OFF_CTR);
  short* Wc[6];
  for (int i = 0; i < 6; ++i) Wc[i] = (short*)(ws + OFF_W + (size_t)i*WSZ);
  short* H0a = (short*)(ws + OFF_H);
  short* H0b = (short*)(ws + OFF_H + HSZ);
  short* H1a = (short*)(ws + OFF_H + 2*HSZ);
  short* H1b = (short*)(ws + OFF_H + 3*HSZ);

  hipMemsetAsync(ws, 0, 8192, stream);          // hdr + barrier counters
  hipMemsetAsync(H0a, 0, HSZ, stream);
  hipMemsetAsync(H1a, 0, HSZ, stream);
  probe1_kernel<<<dim3(1), dim3(256), 0, stream>>>(w_hh0, hdr);

  dim3 cg(1024), cb(256);
  cvt_kernel<<<cg, cb, 0, stream>>>(w_hh0,  Wc[0], hdr);
  cvt_kernel<<<cg, cb, 0, stream>>>(w_ih1,  Wc[1], hdr);
  cvt_kernel<<<cg, cb, 0, stream>>>(w_hh1,  Wc[2], hdr);
  cvt_kernel<<<cg, cb, 0, stream>>>(pw_hh0, Wc[3], hdr);
  cvt_kernel<<<cg, cb, 0, stream>>>(pw_ih1, Wc[4], hdr);
  cvt_kernel<<<cg, cb, 0, stream>>>(pw_hh1, Wc[5], hdr);

  lstm_persist<<<dim3(NBLK), dim3(256), 0, stream>>>(
      x, w_ih0, b_ih0, b_hh0, b_ih1, b_hh1, fc_w, fc_b,
      pw_ih0, pb_ih0, pb_hh0, pb_ih1, pb_hh1, pfc_w, pfc_b,
      Wc[0], Wc[1], Wc[2], Wc[3], Wc[4], Wc[5],
      H0a, H0b, H1a, H1b, ctr, hdr, dout);
}